// Round 7
// baseline (392.568 us; speedup 1.0000x reference)
//
#include <hip/hip_runtime.h>
#include <hip/hip_bf16.h>

#define NN   10000
#define NP   10048          // 157*64 padded rows
#define HID  256
#define BN_EPS 1e-5f
#define NPH  ((size_t)NP * 256)

typedef __bf16 bf16x4 __attribute__((ext_vector_type(4)));
typedef __bf16 bf16x8 __attribute__((ext_vector_type(8)));
typedef float  f32x4  __attribute__((ext_vector_type(4)));

__device__ __forceinline__ void gl_lds16(const void* gptr, void* lptr) {
    __builtin_amdgcn_global_load_lds(
        (const __attribute__((address_space(1))) void*)gptr,
        (__attribute__((address_space(3))) void*)lptr,
        16, 0, 0);
}

// ------------------------------------------------------------------ graph prep
__global__ void prep_zero_detect(const int* __restrict__ e, unsigned* __restrict__ cnt,
                                 unsigned* __restrict__ flag) {
    int i = blockIdx.x * 256 + threadIdx.x;
    if (i < NN) cnt[i] = 0u;
    if (blockIdx.x == 0) {
        __shared__ int nz;
        if (threadIdx.x == 0) nz = 0;
        __syncthreads();
        if (e[2 * threadIdx.x + 1] != 0) nz = 1;
        __syncthreads();
        if (threadIdx.x == 0) *flag = (nz == 0) ? 1u : 0u;  // 1 => int64 layout
    }
}

__device__ __forceinline__ int edge_val(const int* e, unsigned f, long idx) {
    return f ? e[2 * idx] : e[idx];
}

__global__ void count_edges(const int* __restrict__ e, const unsigned* __restrict__ flag,
                            unsigned* __restrict__ cnt, int E) {
    int i = blockIdx.x * blockDim.x + threadIdx.x;
    if (i >= E) return;
    unsigned f = *flag;
    atomicAdd(&cnt[edge_val(e, f, (long)E + i)], 1u);
}

__global__ void scan_dinv(const unsigned* __restrict__ cnt, unsigned* __restrict__ off,
                          unsigned* __restrict__ cur, float* __restrict__ dinv, int n) {
    __shared__ unsigned partial[256];
    int t = threadIdx.x;
    int chunk = (n + 255) / 256;
    int lo = t * chunk;
    int hi = lo + chunk; if (hi > n) hi = n; if (lo > n) lo = n;
    unsigned s = 0;
    for (int i = lo; i < hi; ++i) s += cnt[i];
    partial[t] = s;
    __syncthreads();
    for (int d = 1; d < 256; d <<= 1) {
        unsigned v = (t >= d) ? partial[t - d] : 0u;
        __syncthreads();
        partial[t] += v;
        __syncthreads();
    }
    unsigned base = (t == 0) ? 0u : partial[t - 1];
    for (int i = lo; i < hi; ++i) {
        off[i] = base; cur[i] = base;
        dinv[i] = rsqrtf((float)cnt[i] + 1.0f);
        base += cnt[i];
    }
    if (t == 255) off[n] = base;
}

__global__ void fill_csr(const int* __restrict__ e, const unsigned* __restrict__ flag,
                         unsigned* __restrict__ cur, int* __restrict__ csr_src, int E) {
    int i = blockIdx.x * blockDim.x + threadIdx.x;
    if (i >= E) return;
    unsigned f = *flag;
    int src = edge_val(e, f, (long)i);
    int dst = edge_val(e, f, (long)E + i);
    unsigned pos = atomicAdd(&cur[dst], 1u);
    csr_src[pos] = src;
}

// ------------------------------------------------------------------ weight splits
__global__ void split_all(const float* __restrict__ in_W, const float* __restrict__ gcn_W,
                          const float* __restrict__ c1_W, const float* __restrict__ c2_W,
                          const float* __restrict__ c3_W,
                          __bf16* __restrict__ wih, __bf16* __restrict__ wil,
                          __bf16* __restrict__ gwh, __bf16* __restrict__ gwl,
                          __bf16* __restrict__ c1h, __bf16* __restrict__ c1l,
                          __bf16* __restrict__ c2h, __bf16* __restrict__ c2l,
                          __bf16* __restrict__ c3h, __bf16* __restrict__ c3l) {
    int idx = blockIdx.x * 256 + threadIdx.x;
    float v; __bf16 *dh, *dl; int o;
    if (idx < 524288)      { v = in_W[idx];          dh = wih; dl = wil; o = idx; }
    else if (idx < 720896) { o = idx - 524288; v = gcn_W[o]; dh = gwh; dl = gwl; }
    else if (idx < 753664) { o = idx - 720896; v = c1_W[o];  dh = c1h; dl = c1l; }
    else if (idx < 761856) { o = idx - 753664; v = c2_W[o];  dh = c2h; dl = c2l; }
    else                   { o = idx - 761856; int r = o >> 6, c = o & 63;
                             v = (r < 10) ? c3_W[r * 64 + c] : 0.0f; dh = c3h; dl = c3l; }
    __bf16 h = (__bf16)v;
    dh[o] = h;
    dl[o] = (__bf16)(v - (float)h);
}

// ------------------------------------------------------------------
// Input projection: BM=64 x BN=256, split-K=4 (z). T3/T4 counted-vmcnt
// pipeline: raw s_barrier, NEVER vmcnt(0) in the steady loop.
//  - sBh: TRIPLE-buffered (glB issued 2 iters ahead of use)
//  - sA hi/lo: double-buffered, fed from registers (A fp32 loaded 2 ahead)
//  - B-lo: 2-deep register pipeline (pass-2 MFMAs)
// Per iter issues exactly 10 vmem ops: 4 bl + 2 av + 4 glB.
#define IPZ 4
#define IPKC 512
#define NT   (IPKC / 32)     // 16
__global__ __launch_bounds__(256) void inproj_gemm(
    const float* __restrict__ A,
    const __bf16* __restrict__ Bh, const __bf16* __restrict__ Bl,
    float* __restrict__ P)
{
    __shared__ __align__(16) __bf16 sAh[2][2048], sAl[2][2048];  // 64x32 each, 16 KB
    __shared__ __align__(16) __bf16 sBh[3][8192];                // 256x32 each, 48 KB

    const int tid = threadIdx.x, wid = tid >> 6, lane = tid & 63;
    const int fr = lane & 15, fq = lane >> 4;
    const int bm = blockIdx.x * 64;
    const int kbase = blockIdx.z * IPKC;
    const int wn = wid * 64;

    f32x4 acc[4][4] = {};

    // A staging ids: row rs (0..63), 8-col chunk cq (0..3)
    const int rs = tid >> 2, cq = tid & 3;
    const int gr = min(bm + rs, NN - 1);
    const float* aptr = A + (size_t)gr * 2048 + kbase + cq * 8;
    const int scA = rs * 32 + ((cq ^ ((rs >> 1) & 3)) << 3);
    // B staging ids
    const int brow_l = lane >> 2, bch = lane & 3;

    const __bf16* blp[4];
#pragma unroll
    for (int ni = 0; ni < 4; ++ni)
        blp[ni] = Bl + (size_t)(wn + ni * 16 + fr) * 2048 + kbase + fq * 8;

    // register pipelines (static-indexed post-unroll)
    bf16x8 blr[2][4];          // blr[t&1] = B-lo fragments of tile t
    float  avr[2][8];          // avr[t&1] = A fp32 of tile t (t loaded 2 ahead)

#define LOAD_BL(t, s)                                              \
    {                                                              \
        _Pragma("unroll")                                          \
        for (int ni = 0; ni < 4; ++ni)                             \
            blr[s][ni] = *(const bf16x8*)(blp[ni] + (t) * 32);     \
    }
#define LOAD_AV(t, s)                                              \
    {                                                              \
        float4 u0 = *(const float4*)(aptr + (t) * 32);             \
        float4 u1 = *(const float4*)(aptr + (t) * 32 + 4);         \
        avr[s][0]=u0.x; avr[s][1]=u0.y; avr[s][2]=u0.z; avr[s][3]=u0.w; \
        avr[s][4]=u1.x; avr[s][5]=u1.y; avr[s][6]=u1.z; avr[s][7]=u1.w; \
    }
#define STAGE_B(t)                                                 \
    {                                                              \
        const int nk = kbase + (t) * 32;                           \
        __bf16* dst = &sBh[(t) % 3][0];                            \
        _Pragma("unroll")                                          \
        for (int j = 0; j < 4; ++j) {                              \
            int slice = wid * 4 + j;                               \
            int row = slice * 16 + brow_l;                         \
            int lc = bch ^ ((row >> 1) & 3);                       \
            gl_lds16(Bh + (size_t)row * 2048 + nk + lc * 8, dst + slice * 512); \
        }                                                          \
    }
#define WRITE_SA(s, buf)                                           \
    {                                                              \
        bf16x8 hv, lv;                                             \
        _Pragma("unroll")                                          \
        for (int j = 0; j < 8; ++j) {                              \
            __bf16 h = (__bf16)avr[s][j];                          \
            hv[j] = h; lv[j] = (__bf16)(avr[s][j] - (float)h);     \
        }                                                          \
        *(bf16x8*)&sAh[buf][scA] = hv;                             \
        *(bf16x8*)&sAl[buf][scA] = lv;                             \
    }
#define COMPUTE(k, u)                                              \
    {                                                              \
        const __bf16* sb = &sBh[(k) % 3][0];                       \
        bf16x8 bh[4];                                              \
        _Pragma("unroll")                                          \
        for (int ni = 0; ni < 4; ++ni) {                           \
            int r = wn + ni * 16 + fr;                             \
            bh[ni] = *(const bf16x8*)&sb[r * 32 + ((fq ^ ((r >> 1) & 3)) << 3)]; \
        }                                                          \
        _Pragma("unroll")                                          \
        for (int mi = 0; mi < 4; ++mi) {                           \
            int r = mi * 16 + fr;                                  \
            int e = r * 32 + ((fq ^ ((r >> 1) & 3)) << 3);         \
            bf16x8 ah = *(const bf16x8*)&sAh[u][e];                \
            bf16x8 al = *(const bf16x8*)&sAl[u][e];                \
            _Pragma("unroll")                                      \
            for (int ni = 0; ni < 4; ++ni) {                       \
                acc[mi][ni] = __builtin_amdgcn_mfma_f32_16x16x32_bf16(ah, bh[ni], acc[mi][ni], 0, 0, 0); \
                acc[mi][ni] = __builtin_amdgcn_mfma_f32_16x16x32_bf16(al, bh[ni], acc[mi][ni], 0, 0, 0); \
                acc[mi][ni] = __builtin_amdgcn_mfma_f32_16x16x32_bf16(ah, blr[u][ni], acc[mi][ni], 0, 0, 0); \
            }                                                      \
        }                                                          \
    }

    // ---- prologue: tiles 0,1 in flight; sA[0] written ----
    LOAD_BL(0, 0);
    LOAD_AV(0, 0);
    LOAD_AV(1, 1);
    STAGE_B(0);
    STAGE_B(1);
    WRITE_SA(0, 0);                    // compiler waits av(0) regs
    asm volatile("s_waitcnt vmcnt(4)" ::: "memory");   // glB(0) landed (glB(1)=4 in flight)
    __builtin_amdgcn_sched_barrier(0);
    asm volatile("s_waitcnt lgkmcnt(0)" ::: "memory");
    __builtin_amdgcn_s_barrier();
    __builtin_amdgcn_sched_barrier(0);

    // ---- steady loop: k = 0..13 (kt*2+u), all guards true ----
    for (int kt = 0; kt < 7; ++kt) {
#pragma unroll
        for (int u = 0; u < 2; ++u) {
            const int k = kt * 2 + u;
            LOAD_BL(k + 1, u ^ 1);     // bl(k+1)
            LOAD_AV(k + 2, u);         // av(k+2): slot (k+2)&1 == u
            STAGE_B(k + 2);            // -> sB[(k+2)%3], freed by entry barrier
            __builtin_amdgcn_sched_barrier(0);
            COMPUTE(k, u);
            WRITE_SA(u ^ 1, u ^ 1);    // av(k+1) -> sA[(k+1)&1]
            asm volatile("s_waitcnt vmcnt(10)" ::: "memory");  // glB(k+1) landed
            __builtin_amdgcn_sched_barrier(0);
            asm volatile("s_waitcnt lgkmcnt(0)" ::: "memory");
            __builtin_amdgcn_s_barrier();
            __builtin_amdgcn_sched_barrier(0);
        }
    }
    // ---- k = 14 (u=0) ----
    {
        LOAD_BL(15, 1);
        __builtin_amdgcn_sched_barrier(0);
        COMPUTE(14, 0);
        WRITE_SA(1, 1);                // av(15) -> sA[1]
        asm volatile("s_waitcnt vmcnt(4)" ::: "memory");   // glB(15) landed (bl(15)=4 in flight)
        __builtin_amdgcn_sched_barrier(0);
        asm volatile("s_waitcnt lgkmcnt(0)" ::: "memory");
        __builtin_amdgcn_s_barrier();
        __builtin_amdgcn_sched_barrier(0);
    }
    // ---- k = 15 (u=1) ----
    COMPUTE(15, 1);

#undef LOAD_BL
#undef LOAD_AV
#undef STAGE_B
#undef WRITE_SA
#undef COMPUTE

    float* Pz = P + (size_t)blockIdx.z * NPH;
#pragma unroll
    for (int mi = 0; mi < 4; ++mi) {
        int row0 = bm + mi * 16 + fq * 4;
#pragma unroll
        for (int ni = 0; ni < 4; ++ni) {
            int col = wn + ni * 16 + fr;
#pragma unroll
            for (int r = 0; r < 4; ++r)
                Pz[(size_t)(row0 + r) * 256 + col] = acc[mi][ni][r];
        }
    }
}

// reduce 4 partials + bias + relu -> bf16 hi/lo planes (zero pad rows)
__global__ void inproj_epi(const float* __restrict__ P, const float* __restrict__ b,
                           __bf16* __restrict__ hhi, __bf16* __restrict__ hlo) {
    int t = blockIdx.x * 256 + threadIdx.x;
    size_t idx = (size_t)t * 4;
    int row = (int)(idx >> 8), col = (int)(idx & 255);
    float v[4] = {0, 0, 0, 0};
    if (row < NN) {
        const float* p = P + idx;
        float4 a0 = *(const float4*)(p);
        float4 a1 = *(const float4*)(p + NPH);
        float4 a2 = *(const float4*)(p + 2 * NPH);
        float4 a3 = *(const float4*)(p + 3 * NPH);
        v[0] = fmaxf(a0.x + a1.x + a2.x + a3.x + b[col + 0], 0.0f);
        v[1] = fmaxf(a0.y + a1.y + a2.y + a3.y + b[col + 1], 0.0f);
        v[2] = fmaxf(a0.z + a1.z + a2.z + a3.z + b[col + 2], 0.0f);
        v[3] = fmaxf(a0.w + a1.w + a2.w + a3.w + b[col + 3], 0.0f);
    }
    bf16x4 hv, lv;
#pragma unroll
    for (int j = 0; j < 4; ++j) {
        __bf16 h = (__bf16)v[j];
        hv[j] = h; lv[j] = (__bf16)(v[j] - (float)h);
    }
    *(bf16x4*)&hhi[idx] = hv;
    *(bf16x4*)&hlo[idx] = lv;
}

// ------------------------------------------------------------------
// Layer GEMM (K=256): no LDS, per-lane direct fragment loads.
// Epilogue pre-scales each output row by dinv[row]  ->  hws = (h @ W^T) * dinv
__global__ __launch_bounds__(256) void gemm_layer(
    const __bf16* __restrict__ Ah, const __bf16* __restrict__ Al,
    const __bf16* __restrict__ Bh, const __bf16* __restrict__ Bl,
    const float* __restrict__ dinv, float* __restrict__ Cf)
{
    const int tid = threadIdx.x, wid = tid >> 6, lane = tid & 63;
    const int fr = lane & 15, fq = lane >> 4;
    const int wr = wid >> 1, wc = wid & 1;
    const int bm = blockIdx.x * 64, bn = blockIdx.y * 64;

    f32x4 acc[2][2] = {};
    size_t ra[2], rb[2];
#pragma unroll
    for (int mi = 0; mi < 2; ++mi) ra[mi] = (size_t)(bm + wr * 32 + mi * 16 + fr) * 256 + fq * 8;
#pragma unroll
    for (int ni = 0; ni < 2; ++ni) rb[ni] = (size_t)(bn + wc * 32 + ni * 16 + fr) * 256 + fq * 8;

#pragma unroll
    for (int kt = 0; kt < 8; ++kt) {
        bf16x8 ah[2], al[2], bh[2], bl[2];
#pragma unroll
        for (int mi = 0; mi < 2; ++mi) {
            ah[mi] = *(const bf16x8*)(Ah + ra[mi] + kt * 32);
            al[mi] = *(const bf16x8*)(Al + ra[mi] + kt * 32);
        }
#pragma unroll
        for (int ni = 0; ni < 2; ++ni) {
            bh[ni] = *(const bf16x8*)(Bh + rb[ni] + kt * 32);
            bl[ni] = *(const bf16x8*)(Bl + rb[ni] + kt * 32);
        }
#pragma unroll
        for (int mi = 0; mi < 2; ++mi)
#pragma unroll
            for (int ni = 0; ni < 2; ++ni) {
                acc[mi][ni] = __builtin_amdgcn_mfma_f32_16x16x32_bf16(ah[mi], bh[ni], acc[mi][ni], 0, 0, 0);
                acc[mi][ni] = __builtin_amdgcn_mfma_f32_16x16x32_bf16(ah[mi], bl[ni], acc[mi][ni], 0, 0, 0);
                acc[mi][ni] = __builtin_amdgcn_mfma_f32_16x16x32_bf16(al[mi], bh[ni], acc[mi][ni], 0, 0, 0);
            }
    }

    float dv[2][4];
#pragma unroll
    for (int mi = 0; mi < 2; ++mi)
#pragma unroll
        for (int r = 0; r < 4; ++r) {
            int row = bm + wr * 32 + mi * 16 + fq * 4 + r;
            dv[mi][r] = (row < NN) ? dinv[row] : 0.0f;
        }

#pragma unroll
    for (int mi = 0; mi < 2; ++mi)
#pragma unroll
        for (int ni = 0; ni < 2; ++ni) {
            int col = bn + wc * 32 + ni * 16 + fr;
#pragma unroll
            for (int r = 0; r < 4; ++r) {
                int row = bm + wr * 32 + mi * 16 + fq * 4 + r;
                if (row < NN) Cf[(size_t)row * 256 + col] = acc[mi][ni][r] * dv[mi][r];
            }
        }
}

// ------------------------------------------------------------------
// Wave-per-node GCN aggregate. hws rows are pre-scaled by dinv[src], so
// out = relu(BN(dn*(sum_src hws[src] + hws[self]) + bias)) (+ res).
__global__ __launch_bounds__(256) void gcn_aggregate(
    const float* __restrict__ hws, const float* __restrict__ res,
    const float* __restrict__ dinv, const unsigned* __restrict__ off,
    const int* __restrict__ csr,
    const float* __restrict__ bias, const float* __restrict__ gamma,
    const float* __restrict__ beta, const float* __restrict__ mean,
    const float* __restrict__ var,
    float* __restrict__ hf, __bf16* __restrict__ hhi, __bf16* __restrict__ hlo)
{
    const int wid = threadIdx.x >> 6, l = threadIdx.x & 63;
    const int n = blockIdx.x * 4 + wid;          // grid = NN/4 blocks
    const int f4 = l << 2;
    const size_t rowb = (size_t)n * HID + f4;

    const float dn = dinv[n];
    const unsigned j0 = off[n], j1 = off[n + 1];
    f32x4 acc = *(const f32x4*)(hws + rowb);     // self-loop term (pre-scaled)

    for (unsigned base = j0; base < j1; base += 64) {
        int cnt = (int)(j1 - base); if (cnt > 64) cnt = 64;
        int sl = (base + (unsigned)l < j1) ? csr[base + l] : 0;
#pragma unroll 4
        for (int jj = 0; jj < cnt; ++jj) {
            int s = __shfl(sl, jj);
            acc += *(const f32x4*)(hws + (size_t)s * HID + f4);
        }
    }

    f32x4 b4  = *(const f32x4*)(bias + f4);
    f32x4 m4  = *(const f32x4*)(mean + f4);
    f32x4 v4  = *(const f32x4*)(var + f4);
    f32x4 g4  = *(const f32x4*)(gamma + f4);
    f32x4 be4 = *(const f32x4*)(beta + f4);
    f32x4 r4 = {0.0f, 0.0f, 0.0f, 0.0f};
    if (res) r4 = *(const f32x4*)(res + rowb);

    f32x4 o;
    bf16x4 hv, lv;
#pragma unroll
    for (int j = 0; j < 4; ++j) {
        float t = dn * acc[j] + b4[j];
        t = (t - m4[j]) * rsqrtf(v4[j] + BN_EPS) * g4[j] + be4[j];
        t = fmaxf(t, 0.0f);
        t += r4[j];
        o[j] = t;
        __bf16 h = (__bf16)t;
        hv[j] = h; lv[j] = (__bf16)(t - (float)h);
    }
    if (hf) *(f32x4*)(hf + rowb) = o;
    *(bf16x4*)&hhi[rowb] = hv;
    *(bf16x4*)&hlo[rowb] = lv;
}

// ------------------------------------------------------------------
// Fused classifier: 32-row tile, h -> O1(LDS) -> O2(LDS) -> logits.
__global__ __launch_bounds__(256) void classifier(
    const __bf16* __restrict__ Ah, const __bf16* __restrict__ Al,
    const __bf16* __restrict__ c1h, const __bf16* __restrict__ c1l, const float* __restrict__ b1,
    const __bf16* __restrict__ c2h, const __bf16* __restrict__ c2l, const float* __restrict__ b2,
    const __bf16* __restrict__ c3h, const __bf16* __restrict__ c3l, const float* __restrict__ b3,
    float* __restrict__ out)
{
    __shared__ __align__(16) float sO1[32][132];
    __shared__ __align__(16) float sO2[32][68];

    const int tid = threadIdx.x, wid = tid >> 6, lane = tid & 63;
    const int fr = lane & 15, fq = lane >> 4;
    const int bm = blockIdx.x * 32;

    // ---- stage 1: O1 = relu(h @ c1^T + b1)   M=32 N=128 K=256
    {
        f32x4 acc[2][2] = {};
        size_t ra[2], rb[2];
#pragma unroll
        for (int mi = 0; mi < 2; ++mi) ra[mi] = (size_t)(bm + mi * 16 + fr) * 256 + fq * 8;
#pragma unroll
        for (int ni = 0; ni < 2; ++ni) rb[ni] = (size_t)(wid * 32 + ni * 16 + fr) * 256 + fq * 8;
#pragma unroll
        for (int kt = 0; kt < 8; ++kt) {
            bf16x8 ah[2], al[2], bh[2], bl[2];
#pragma unroll
            for (int mi = 0; mi < 2; ++mi) {
                ah[mi] = *(const bf16x8*)(Ah + ra[mi] + kt * 32);
                al[mi] = *(const bf16x8*)(Al + ra[mi] + kt * 32);
            }
#pragma unroll
            for (int ni = 0; ni < 2; ++ni) {
                bh[ni] = *(const bf16x8*)(c1h + rb[ni] + kt * 32);
                bl[ni] = *(const bf16x8*)(c1l + rb[ni] + kt * 32);
            }
#pragma unroll
            for (int mi = 0; mi < 2; ++mi)
#pragma unroll
                for (int ni = 0; ni < 2; ++ni) {
                    acc[mi][ni] = __builtin_amdgcn_mfma_f32_16x16x32_bf16(ah[mi], bh[ni], acc[mi][ni], 0, 0, 0);
                    acc[mi][ni] = __builtin_amdgcn_mfma_f32_16x16x32_bf16(ah[mi], bl[ni], acc[mi][ni], 0, 0, 0);
                    acc[mi][ni] = __builtin_amdgcn_mfma_f32_16x16x32_bf16(al[mi], bh[ni], acc[mi][ni], 0, 0, 0);
                }
        }
#pragma unroll
        for (int mi = 0; mi < 2; ++mi)
#pragma unroll
            for (int ni = 0; ni < 2; ++ni) {
                int col = wid * 32 + ni * 16 + fr;
                float bb = b1[col];
#pragma unroll
                for (int r = 0; r < 4; ++r)
                    sO1[mi * 16 + fq * 4 + r][col] = fmaxf(acc[mi][ni][r] + bb, 0.0f);
            }
    }
    __syncthreads();

    // ---- stage 2: O2 = relu(O1 @ c2^T + b2)   M=32 N=64 K=128
    {
        f32x4 acc[2] = {};
#pragma unroll
        for (int kt = 0; kt < 4; ++kt) {
            bf16x8 ah[2], al[2];
#pragma unroll
            for (int mi = 0; mi < 2; ++mi) {
                const float* p = &sO1[mi * 16 + fr][kt * 32 + fq * 8];
                f32x4 v0 = *(const f32x4*)p;
                f32x4 v1 = *(const f32x4*)(p + 4);
                float vv[8] = {v0[0], v0[1], v0[2], v0[3], v1[0], v1[1], v1[2], v1[3]};
#pragma unroll
                for (int j = 0; j < 8; ++j) {
                    __bf16 h = (__bf16)vv[j];
                    ah[mi][j] = h; al[mi][j] = (__bf16)(vv[j] - (float)h);
                }
            }
            size_t rb = (size_t)(wid * 16 + fr) * 128 + kt * 32 + fq * 8;
            bf16x8 bh = *(const bf16x8*)(c2h + rb);
            bf16x8 bl = *(const bf16x8*)(c2l + rb);
#pragma unroll
            for (int mi = 0; mi < 2; ++mi) {
                acc[mi] = __builtin_amdgcn_mfma_f32_16x16x32_bf16(ah[mi], bh, acc[mi], 0, 0, 0);
                acc[mi] = __builtin_amdgcn_mfma_f32_16x16x32_bf16(ah[mi], bl, acc[mi], 0, 0, 0);
                acc[mi] = __builtin_amdgcn_mfma_f32_16x16x32_bf16(al[mi], bh, acc[mi], 0, 0, 0);
            }
        }
        int col = wid * 16 + fr;
        float bb = b2[col];
#pragma unroll
        for (int mi = 0; mi < 2; ++mi)
#pragma unroll
            for (int r = 0; r < 4; ++r)
                sO2[mi * 16 + fq * 4 + r][col] = fmaxf(acc[mi][r] + bb, 0.0f);
    }
    __syncthreads();

    // ---- stage 3: logits = O2 @ c3^T + b3
    if (wid < 2) {
        f32x4 acc = {};
#pragma unroll
        for (int kt = 0; kt < 2; ++kt) {
            const float* p = &sO2[wid * 16 + fr][kt * 32 + fq * 8];
            f32x4 v0 = *(const f32x4*)p;
            f32x4 v1 = *(const f32x4*)(p + 4);
            float vv[8] = {v0[0], v0[1], v0[2], v0[3], v1[0], v1[1], v1[2], v1[3]};
            bf16x8 ah, al;
#pragma unroll
            for (int j = 0; j < 8; ++j) {
                __bf16 h = (__bf16)vv[j];
                ah[j] = h; al[j] = (__bf16)(vv[j] - (float)h);
            }
            size_t rb = (size_t)fr * 64 + kt * 32 + fq * 8;
            bf16x8 bh = *(const bf16x8*)(c3h + rb);
            bf16x8 bl = *(const bf16x8*)(c3l + rb);
            acc = __builtin_amdgcn_mfma_f32_16x16x32_bf16(ah, bh, acc, 0, 0, 0);
            acc = __builtin_amdgcn_mfma_f32_16x16x32_bf16(ah, bl, acc, 0, 0, 0);
            acc = __builtin_amdgcn_mfma_f32_16x16x32_bf16(al, bh, acc, 0, 0, 0);
        }
        if (fr < 10) {
            float bb = b3[fr];
#pragma unroll
            for (int r = 0; r < 4; ++r) {
                int row = bm + wid * 16 + fq * 4 + r;
                if (row < NN) out[(size_t)row * 10 + fr] = acc[r] + bb;
            }
        }
    }
}

// ------------------------------------------------------------------
extern "C" void kernel_launch(void* const* d_in, const int* in_sizes, int n_in,
                              void* d_out, int out_size, void* d_ws, size_t ws_size,
                              hipStream_t stream)
{
    const float* x     = (const float*)d_in[0];
    const int*   eidx  = (const int*)d_in[1];
    const float* in_W  = (const float*)d_in[2];
    const float* in_b  = (const float*)d_in[3];
    const float* gcn_W = (const float*)d_in[4];
    const float* gcn_b = (const float*)d_in[5];
    const float* bn_g  = (const float*)d_in[6];
    const float* bn_be = (const float*)d_in[7];
    const float* bn_m  = (const float*)d_in[8];
    const float* bn_v  = (const float*)d_in[9];
    const float* c1_W  = (const float*)d_in[10];
    const float* c1_b  = (const float*)d_in[11];
    const float* c2_W  = (const float*)d_in[12];
    const float* c2_b  = (const float*)d_in[13];
    const float* c3_W  = (const float*)d_in[14];
    const float* c3_b  = (const float*)d_in[15];
    float* out = (float*)d_out;

    const int E = in_sizes[1] / 2;
    float* ws = (float*)d_ws;

    // ---- workspace layout ----
    float*  P   = ws;                 // 4 slices of NPH f32 (reused as h1,h2,hws)
    float*  h1  = P;
    float*  h2  = P + NPH;
    float*  hws = P + 2 * NPH;
    __bf16* hhi = (__bf16*)(P + 4 * NPH);
    __bf16* hlo = hhi + NPH;
    __bf16* wih = hlo + NPH;          // 256x2048
    __bf16* wil = wih + 524288;
    __bf16* gwh = wil + 524288;       // 768x256
    __bf16* gwl = gwh + 196608;
    __bf16* c1h = gwl + 196608;       // 128x256
    __bf16* c1l = c1h + 32768;
    __bf16* c2h = c1l + 32768;        // 64x128
    __bf16* c2l = c2h + 8192;
    __bf16* c3h = c2l + 8192;         // 16x64 (10 real rows)
    __bf16* c3l = c3h + 1024;
    float*    dinv = (float*)(c3l + 1024);
    unsigned* cnt  = (unsigned*)(dinv + NN);
    unsigned* off  = cnt + NN;
    unsigned* cur  = off + NN + 1;
    unsigned* flag = cur + NN;
    int*      csr  = (int*)(flag + 4);

    // ---- graph prep ----
    prep_zero_detect<<<40, 256, 0, stream>>>(eidx, cnt, flag);
    count_edges<<<(E + 255) / 256, 256, 0, stream>>>(eidx, flag, cnt, E);
    scan_dinv<<<1, 256, 0, stream>>>(cnt, off, cur, dinv, NN);
    fill_csr<<<(E + 255) / 256, 256, 0, stream>>>(eidx, flag, cur, csr, E);

    // ---- weight splits ----
    split_all<<<2980, 256, 0, stream>>>(in_W, gcn_W, c1_W, c2_W, c3_W,
                                        wih, wil, gwh, gwl, c1h, c1l, c2h, c2l, c3h, c3l);

    // ---- input projection ----
    inproj_gemm<<<dim3(NP / 64, 1, IPZ), 256, 0, stream>>>(x, wih, wil, P);
    inproj_epi<<<(int)(NPH / 1024), 256, 0, stream>>>(P, in_b, hhi, hlo);

    // ---- 3 GCN layers ----
    for (int i = 0; i < 3; ++i) {
        gemm_layer<<<dim3(NP / 64, 4), 256, 0, stream>>>(
            hhi, hlo, gwh + (size_t)i * 65536, gwl + (size_t)i * 65536, dinv, hws);
        const float* res = (i == 0) ? nullptr : (i == 1 ? h1 : h2);
        float* hf = (i == 0) ? h1 : (i == 1 ? h2 : nullptr);
        gcn_aggregate<<<NN / 4, 256, 0, stream>>>(
            hws, res, dinv, off, csr,
            gcn_b + i * HID, bn_g + i * HID, bn_be + i * HID,
            bn_m + i * HID, bn_v + i * HID, hf, hhi, hlo);
    }

    // ---- fused classifier ----
    classifier<<<NP / 32, 256, 0, stream>>>(hhi, hlo, c1h, c1l, c1_b,
                                            c2h, c2l, c2_b, c3h, c3l, c3_b, out);
}

// Round 8
// 344.141 us; speedup vs baseline: 1.1407x; 1.1407x over previous
//
#include <hip/hip_runtime.h>
#include <hip/hip_bf16.h>

#define NN   10000
#define NP   10048          // 157*64 padded rows
#define HID  256
#define BN_EPS 1e-5f
#define NPH  ((size_t)NP * 256)

typedef __bf16 bf16x4 __attribute__((ext_vector_type(4)));
typedef __bf16 bf16x8 __attribute__((ext_vector_type(8)));
typedef float  f32x4  __attribute__((ext_vector_type(4)));

__device__ __forceinline__ void gl_lds16(const void* gptr, void* lptr) {
    __builtin_amdgcn_global_load_lds(
        (const __attribute__((address_space(1))) void*)gptr,
        (__attribute__((address_space(3))) void*)lptr,
        16, 0, 0);
}

// ------------------------------------------------------------------ graph prep
__global__ void prep_zero_detect(const int* __restrict__ e, unsigned* __restrict__ cnt,
                                 unsigned* __restrict__ flag) {
    int i = blockIdx.x * 256 + threadIdx.x;
    if (i < NN) cnt[i] = 0u;
    if (blockIdx.x == 0) {
        __shared__ int nz;
        if (threadIdx.x == 0) nz = 0;
        __syncthreads();
        if (e[2 * threadIdx.x + 1] != 0) nz = 1;
        __syncthreads();
        if (threadIdx.x == 0) *flag = (nz == 0) ? 1u : 0u;  // 1 => int64 layout
    }
}

__device__ __forceinline__ int edge_val(const int* e, unsigned f, long idx) {
    return f ? e[2 * idx] : e[idx];
}

__global__ void count_edges(const int* __restrict__ e, const unsigned* __restrict__ flag,
                            unsigned* __restrict__ cnt, int E) {
    int i = blockIdx.x * blockDim.x + threadIdx.x;
    if (i >= E) return;
    unsigned f = *flag;
    atomicAdd(&cnt[edge_val(e, f, (long)E + i)], 1u);
}

__global__ void scan_dinv(const unsigned* __restrict__ cnt, unsigned* __restrict__ off,
                          unsigned* __restrict__ cur, float* __restrict__ dinv, int n) {
    __shared__ unsigned partial[256];
    int t = threadIdx.x;
    int chunk = (n + 255) / 256;
    int lo = t * chunk;
    int hi = lo + chunk; if (hi > n) hi = n; if (lo > n) lo = n;
    unsigned s = 0;
    for (int i = lo; i < hi; ++i) s += cnt[i];
    partial[t] = s;
    __syncthreads();
    for (int d = 1; d < 256; d <<= 1) {
        unsigned v = (t >= d) ? partial[t - d] : 0u;
        __syncthreads();
        partial[t] += v;
        __syncthreads();
    }
    unsigned base = (t == 0) ? 0u : partial[t - 1];
    for (int i = lo; i < hi; ++i) {
        off[i] = base; cur[i] = base;
        dinv[i] = rsqrtf((float)cnt[i] + 1.0f);
        base += cnt[i];
    }
    if (t == 255) off[n] = base;
}

__global__ void fill_csr(const int* __restrict__ e, const unsigned* __restrict__ flag,
                         unsigned* __restrict__ cur, int* __restrict__ csr_src, int E) {
    int i = blockIdx.x * blockDim.x + threadIdx.x;
    if (i >= E) return;
    unsigned f = *flag;
    int src = edge_val(e, f, (long)i);
    int dst = edge_val(e, f, (long)E + i);
    unsigned pos = atomicAdd(&cur[dst], 1u);
    csr_src[pos] = src;
}

// ------------------------------------------------------------------ weight splits
__global__ void split_all(const float* __restrict__ in_W, const float* __restrict__ gcn_W,
                          const float* __restrict__ c1_W, const float* __restrict__ c2_W,
                          const float* __restrict__ c3_W,
                          __bf16* __restrict__ wih, __bf16* __restrict__ wil,
                          __bf16* __restrict__ gwh, __bf16* __restrict__ gwl,
                          __bf16* __restrict__ c1h, __bf16* __restrict__ c1l,
                          __bf16* __restrict__ c2h, __bf16* __restrict__ c2l,
                          __bf16* __restrict__ c3h, __bf16* __restrict__ c3l) {
    int idx = blockIdx.x * 256 + threadIdx.x;
    float v; __bf16 *dh, *dl; int o;
    if (idx < 524288)      { v = in_W[idx];          dh = wih; dl = wil; o = idx; }
    else if (idx < 720896) { o = idx - 524288; v = gcn_W[o]; dh = gwh; dl = gwl; }
    else if (idx < 753664) { o = idx - 720896; v = c1_W[o];  dh = c1h; dl = c1l; }
    else if (idx < 761856) { o = idx - 753664; v = c2_W[o];  dh = c2h; dl = c2l; }
    else                   { o = idx - 761856; int r = o >> 6, c = o & 63;
                             v = (r < 10) ? c3_W[r * 64 + c] : 0.0f; dh = c3h; dl = c3l; }
    __bf16 h = (__bf16)v;
    dh[o] = h;
    dl[o] = (__bf16)(v - (float)h);
}

// ------------------------------------------------------------------
// Input projection (round-3 measured-best variant, 80.6 us): BM=64 x BN=256,
// split-K=4, 2-phase pipelined, double-buffered LDS; B hi+lo via
// global_load_lds; A fp32 loads issued early / converted late.
#define IPZ 4
#define IPKC 512
__global__ __launch_bounds__(256) void inproj_gemm(
    const float* __restrict__ A,
    const __bf16* __restrict__ Bh, const __bf16* __restrict__ Bl,
    float* __restrict__ P)
{
    __shared__ __align__(16) __bf16 sAh[2][2048], sAl[2][2048];
    __shared__ __align__(16) __bf16 sBh[2][8192], sBl[2][8192];

    const int tid = threadIdx.x, wid = tid >> 6, lane = tid & 63;
    const int fr = lane & 15, fq = lane >> 4;
    const int bm = blockIdx.x * 64;
    const int kbase = blockIdx.z * IPKC;
    const int wn = wid * 64;

    f32x4 acc[4][4] = {};

    const int rs = tid >> 2, cq = tid & 3;
    const int gr = min(bm + rs, NN - 1);
    const float* aptr = A + (size_t)gr * 2048 + cq * 8;
    const int scA = rs * 32 + ((cq ^ ((rs >> 1) & 3)) << 3);
    const int brow_l = lane >> 2, bch = lane & 3;

    float av[8];
    int cur = 0;

    {   // prologue: stage tile 0
        float4 v0 = *(const float4*)(aptr + kbase);
        float4 v1 = *(const float4*)(aptr + kbase + 4);
        av[0]=v0.x; av[1]=v0.y; av[2]=v0.z; av[3]=v0.w;
        av[4]=v1.x; av[5]=v1.y; av[6]=v1.z; av[7]=v1.w;
#pragma unroll
        for (int j = 0; j < 4; ++j) {
            int slice = wid * 4 + j;
            int row = slice * 16 + brow_l;
            int lc = bch ^ ((row >> 1) & 3);
            size_t goff = (size_t)row * 2048 + kbase + lc * 8;
            gl_lds16(Bh + goff, &sBh[0][slice * 512]);
            gl_lds16(Bl + goff, &sBl[0][slice * 512]);
        }
        bf16x8 hv, lv;
#pragma unroll
        for (int j = 0; j < 8; ++j) {
            __bf16 h = (__bf16)av[j];
            hv[j] = h; lv[j] = (__bf16)(av[j] - (float)h);
        }
        *(bf16x8*)&sAh[0][scA] = hv;
        *(bf16x8*)&sAl[0][scA] = lv;
    }
    __syncthreads();

    for (int kt = 0; kt < IPKC / 32; ++kt) {
        const bool more = (kt + 1) < IPKC / 32;
        const int nk = kbase + (kt + 1) * 32;
        if (more) {
            float4 v0 = *(const float4*)(aptr + nk);
            float4 v1 = *(const float4*)(aptr + nk + 4);
            av[0]=v0.x; av[1]=v0.y; av[2]=v0.z; av[3]=v0.w;
            av[4]=v1.x; av[5]=v1.y; av[6]=v1.z; av[7]=v1.w;
#pragma unroll
            for (int j = 0; j < 4; ++j) {
                int slice = wid * 4 + j;
                int row = slice * 16 + brow_l;
                int lc = bch ^ ((row >> 1) & 3);
                size_t goff = (size_t)row * 2048 + nk + lc * 8;
                gl_lds16(Bh + goff, &sBh[cur ^ 1][slice * 512]);
                gl_lds16(Bl + goff, &sBl[cur ^ 1][slice * 512]);
            }
        }
        bf16x8 bh[4], bl[4];
#pragma unroll
        for (int ni = 0; ni < 4; ++ni) {
            int r = wn + ni * 16 + fr;
            int e = r * 32 + ((fq ^ ((r >> 1) & 3)) << 3);
            bh[ni] = *(const bf16x8*)&sBh[cur][e];
            bl[ni] = *(const bf16x8*)&sBl[cur][e];
        }
#pragma unroll
        for (int mi = 0; mi < 4; ++mi) {
            int r = mi * 16 + fr;
            int e = r * 32 + ((fq ^ ((r >> 1) & 3)) << 3);
            bf16x8 ah = *(const bf16x8*)&sAh[cur][e];
            bf16x8 al = *(const bf16x8*)&sAl[cur][e];
#pragma unroll
            for (int ni = 0; ni < 4; ++ni) {
                acc[mi][ni] = __builtin_amdgcn_mfma_f32_16x16x32_bf16(ah, bh[ni], acc[mi][ni], 0, 0, 0);
                acc[mi][ni] = __builtin_amdgcn_mfma_f32_16x16x32_bf16(ah, bl[ni], acc[mi][ni], 0, 0, 0);
                acc[mi][ni] = __builtin_amdgcn_mfma_f32_16x16x32_bf16(al, bh[ni], acc[mi][ni], 0, 0, 0);
            }
        }
        if (more) {
            bf16x8 hv, lv;
#pragma unroll
            for (int j = 0; j < 8; ++j) {
                __bf16 h = (__bf16)av[j];
                hv[j] = h; lv[j] = (__bf16)(av[j] - (float)h);
            }
            *(bf16x8*)&sAh[cur ^ 1][scA] = hv;
            *(bf16x8*)&sAl[cur ^ 1][scA] = lv;
        }
        __syncthreads();
        cur ^= 1;
    }

    float* Pz = P + (size_t)blockIdx.z * NPH;
#pragma unroll
    for (int mi = 0; mi < 4; ++mi) {
        int row0 = bm + mi * 16 + fq * 4;
#pragma unroll
        for (int ni = 0; ni < 4; ++ni) {
            int col = wn + ni * 16 + fr;
#pragma unroll
            for (int r = 0; r < 4; ++r)
                Pz[(size_t)(row0 + r) * 256 + col] = acc[mi][ni][r];
        }
    }
}

// reduce 4 partials + bias + relu -> bf16 hi/lo planes (zero pad rows)
__global__ void inproj_epi(const float* __restrict__ P, const float* __restrict__ b,
                           __bf16* __restrict__ hhi, __bf16* __restrict__ hlo) {
    int t = blockIdx.x * 256 + threadIdx.x;
    size_t idx = (size_t)t * 4;
    int row = (int)(idx >> 8), col = (int)(idx & 255);
    float v[4] = {0, 0, 0, 0};
    if (row < NN) {
        const float* p = P + idx;
        float4 a0 = *(const float4*)(p);
        float4 a1 = *(const float4*)(p + NPH);
        float4 a2 = *(const float4*)(p + 2 * NPH);
        float4 a3 = *(const float4*)(p + 3 * NPH);
        v[0] = fmaxf(a0.x + a1.x + a2.x + a3.x + b[col + 0], 0.0f);
        v[1] = fmaxf(a0.y + a1.y + a2.y + a3.y + b[col + 1], 0.0f);
        v[2] = fmaxf(a0.z + a1.z + a2.z + a3.z + b[col + 2], 0.0f);
        v[3] = fmaxf(a0.w + a1.w + a2.w + a3.w + b[col + 3], 0.0f);
    }
    bf16x4 hv, lv;
#pragma unroll
    for (int j = 0; j < 4; ++j) {
        __bf16 h = (__bf16)v[j];
        hv[j] = h; lv[j] = (__bf16)(v[j] - (float)h);
    }
    *(bf16x4*)&hhi[idx] = hv;
    *(bf16x4*)&hlo[idx] = lv;
}

// ------------------------------------------------------------------
// Layer GEMM (K=256): no LDS, per-lane direct fragment loads.
// Epilogue pre-scales each output row by dinv[row]  ->  hws = (h @ W^T) * dinv
__global__ __launch_bounds__(256) void gemm_layer(
    const __bf16* __restrict__ Ah, const __bf16* __restrict__ Al,
    const __bf16* __restrict__ Bh, const __bf16* __restrict__ Bl,
    const float* __restrict__ dinv, float* __restrict__ Cf)
{
    const int tid = threadIdx.x, wid = tid >> 6, lane = tid & 63;
    const int fr = lane & 15, fq = lane >> 4;
    const int wr = wid >> 1, wc = wid & 1;
    const int bm = blockIdx.x * 64, bn = blockIdx.y * 64;

    f32x4 acc[2][2] = {};
    size_t ra[2], rb[2];
#pragma unroll
    for (int mi = 0; mi < 2; ++mi) ra[mi] = (size_t)(bm + wr * 32 + mi * 16 + fr) * 256 + fq * 8;
#pragma unroll
    for (int ni = 0; ni < 2; ++ni) rb[ni] = (size_t)(bn + wc * 32 + ni * 16 + fr) * 256 + fq * 8;

#pragma unroll
    for (int kt = 0; kt < 8; ++kt) {
        bf16x8 ah[2], al[2], bh[2], bl[2];
#pragma unroll
        for (int mi = 0; mi < 2; ++mi) {
            ah[mi] = *(const bf16x8*)(Ah + ra[mi] + kt * 32);
            al[mi] = *(const bf16x8*)(Al + ra[mi] + kt * 32);
        }
#pragma unroll
        for (int ni = 0; ni < 2; ++ni) {
            bh[ni] = *(const bf16x8*)(Bh + rb[ni] + kt * 32);
            bl[ni] = *(const bf16x8*)(Bl + rb[ni] + kt * 32);
        }
#pragma unroll
        for (int mi = 0; mi < 2; ++mi)
#pragma unroll
            for (int ni = 0; ni < 2; ++ni) {
                acc[mi][ni] = __builtin_amdgcn_mfma_f32_16x16x32_bf16(ah[mi], bh[ni], acc[mi][ni], 0, 0, 0);
                acc[mi][ni] = __builtin_amdgcn_mfma_f32_16x16x32_bf16(ah[mi], bl[ni], acc[mi][ni], 0, 0, 0);
                acc[mi][ni] = __builtin_amdgcn_mfma_f32_16x16x32_bf16(al[mi], bh[ni], acc[mi][ni], 0, 0, 0);
            }
    }

    float dv[2][4];
#pragma unroll
    for (int mi = 0; mi < 2; ++mi)
#pragma unroll
        for (int r = 0; r < 4; ++r) {
            int row = bm + wr * 32 + mi * 16 + fq * 4 + r;
            dv[mi][r] = (row < NN) ? dinv[row] : 0.0f;
        }

#pragma unroll
    for (int mi = 0; mi < 2; ++mi)
#pragma unroll
        for (int ni = 0; ni < 2; ++ni) {
            int col = bn + wc * 32 + ni * 16 + fr;
#pragma unroll
            for (int r = 0; r < 4; ++r) {
                int row = bm + wr * 32 + mi * 16 + fq * 4 + r;
                if (row < NN) Cf[(size_t)row * 256 + col] = acc[mi][ni][r] * dv[mi][r];
            }
        }
}

// ------------------------------------------------------------------
// XCD-pinned, feature-chunked GCN aggregate.
// 4 chunks of 64 features; per-chunk gather working set = 10000*256B = 2.56 MB
// < 4 MB per-XCD L2. xcd = bid&7 (round-robin heuristic); chunk = xcd>>1 so
// chunk c only runs on XCDs {2c,2c+1}. 16 lanes per node (f32x4 each).
// Same f32 math/order as before: out = relu(BN(dn*(sum+self) + bias)) (+res).
__global__ __launch_bounds__(256) void gcn_aggregate(
    const float* __restrict__ hws, const float* __restrict__ res,
    const float* __restrict__ dinv, const unsigned* __restrict__ off,
    const int* __restrict__ csr,
    const float* __restrict__ bias, const float* __restrict__ gamma,
    const float* __restrict__ beta, const float* __restrict__ mean,
    const float* __restrict__ var,
    float* __restrict__ hf, __bf16* __restrict__ hhi, __bf16* __restrict__ hlo)
{
    const int xcd = blockIdx.x & 7;
    const int chunk = xcd >> 1;                      // 0..3
    const int nb = (blockIdx.x >> 3) * 2 + (xcd & 1); // node-block 0..625
    if (nb >= 625) return;                            // 625*16 = 10000 exactly

    const int tid = threadIdx.x, l = tid & 63;
    const int g = tid >> 4;                           // node-in-block 0..15
    const int q = tid & 15;                           // feature lane 0..15
    const int node = nb * 16 + g;
    const int f = chunk * 64 + q * 4;
    const size_t rowb = (size_t)node * HID + f;

    const float dn = dinv[node];
    const unsigned j0 = off[node], j1 = off[node + 1];
    f32x4 acc = *(const f32x4*)(hws + rowb);          // self term (pre-scaled)

    const int gbase = l & 48;                         // shfl group base in wave
    for (unsigned base = j0; base < j1; base += 16) {
        int cnt = (int)(j1 - base); if (cnt > 16) cnt = 16;
        int sl = (base + (unsigned)q < j1) ? csr[base + q] : 0;
#pragma unroll 4
        for (int jj = 0; jj < cnt; ++jj) {
            int s = __shfl(sl, gbase + jj);
            acc += *(const f32x4*)(hws + (size_t)s * HID + f);
        }
    }

    f32x4 b4  = *(const f32x4*)(bias + f);
    f32x4 m4  = *(const f32x4*)(mean + f);
    f32x4 v4  = *(const f32x4*)(var + f);
    f32x4 g4  = *(const f32x4*)(gamma + f);
    f32x4 be4 = *(const f32x4*)(beta + f);
    f32x4 r4 = {0.0f, 0.0f, 0.0f, 0.0f};
    if (res) r4 = *(const f32x4*)(res + rowb);

    f32x4 o;
    bf16x4 hv, lv;
#pragma unroll
    for (int j = 0; j < 4; ++j) {
        float t = dn * acc[j] + b4[j];
        t = (t - m4[j]) * rsqrtf(v4[j] + BN_EPS) * g4[j] + be4[j];
        t = fmaxf(t, 0.0f);
        t += r4[j];
        o[j] = t;
        __bf16 h = (__bf16)t;
        hv[j] = h; lv[j] = (__bf16)(t - (float)h);
    }
    if (hf) *(f32x4*)(hf + rowb) = o;
    *(bf16x4*)&hhi[rowb] = hv;
    *(bf16x4*)&hlo[rowb] = lv;
}

// zero the pad rows of the bf16 planes once (aggregate no longer writes them)
__global__ void zero_pad_rows(__bf16* __restrict__ hhi, __bf16* __restrict__ hlo) {
    size_t idx = (size_t)NN * HID + blockIdx.x * 256 + threadIdx.x;  // 48 rows * 256
    hhi[idx] = (__bf16)0.0f;
    hlo[idx] = (__bf16)0.0f;
}

// ------------------------------------------------------------------
// Fused classifier: 32-row tile, h -> O1(LDS) -> O2(LDS) -> logits.
__global__ __launch_bounds__(256) void classifier(
    const __bf16* __restrict__ Ah, const __bf16* __restrict__ Al,
    const __bf16* __restrict__ c1h, const __bf16* __restrict__ c1l, const float* __restrict__ b1,
    const __bf16* __restrict__ c2h, const __bf16* __restrict__ c2l, const float* __restrict__ b2,
    const __bf16* __restrict__ c3h, const __bf16* __restrict__ c3l, const float* __restrict__ b3,
    float* __restrict__ out)
{
    __shared__ __align__(16) float sO1[32][132];
    __shared__ __align__(16) float sO2[32][68];

    const int tid = threadIdx.x, wid = tid >> 6, lane = tid & 63;
    const int fr = lane & 15, fq = lane >> 4;
    const int bm = blockIdx.x * 32;

    // ---- stage 1: O1 = relu(h @ c1^T + b1)   M=32 N=128 K=256
    {
        f32x4 acc[2][2] = {};
        size_t ra[2], rb[2];
#pragma unroll
        for (int mi = 0; mi < 2; ++mi) ra[mi] = (size_t)(bm + mi * 16 + fr) * 256 + fq * 8;
#pragma unroll
        for (int ni = 0; ni < 2; ++ni) rb[ni] = (size_t)(wid * 32 + ni * 16 + fr) * 256 + fq * 8;
#pragma unroll
        for (int kt = 0; kt < 8; ++kt) {
            bf16x8 ah[2], al[2], bh[2], bl[2];
#pragma unroll
            for (int mi = 0; mi < 2; ++mi) {
                ah[mi] = *(const bf16x8*)(Ah + ra[mi] + kt * 32);
                al[mi] = *(const bf16x8*)(Al + ra[mi] + kt * 32);
            }
#pragma unroll
            for (int ni = 0; ni < 2; ++ni) {
                bh[ni] = *(const bf16x8*)(c1h + rb[ni] + kt * 32);
                bl[ni] = *(const bf16x8*)(c1l + rb[ni] + kt * 32);
            }
#pragma unroll
            for (int mi = 0; mi < 2; ++mi)
#pragma unroll
                for (int ni = 0; ni < 2; ++ni) {
                    acc[mi][ni] = __builtin_amdgcn_mfma_f32_16x16x32_bf16(ah[mi], bh[ni], acc[mi][ni], 0, 0, 0);
                    acc[mi][ni] = __builtin_amdgcn_mfma_f32_16x16x32_bf16(ah[mi], bl[ni], acc[mi][ni], 0, 0, 0);
                    acc[mi][ni] = __builtin_amdgcn_mfma_f32_16x16x32_bf16(al[mi], bh[ni], acc[mi][ni], 0, 0, 0);
                }
        }
#pragma unroll
        for (int mi = 0; mi < 2; ++mi)
#pragma unroll
            for (int ni = 0; ni < 2; ++ni) {
                int col = wid * 32 + ni * 16 + fr;
                float bb = b1[col];
#pragma unroll
                for (int r = 0; r < 4; ++r)
                    sO1[mi * 16 + fq * 4 + r][col] = fmaxf(acc[mi][ni][r] + bb, 0.0f);
            }
    }
    __syncthreads();

    // ---- stage 2: O2 = relu(O1 @ c2^T + b2)   M=32 N=64 K=128
    {
        f32x4 acc[2] = {};
#pragma unroll
        for (int kt = 0; kt < 4; ++kt) {
            bf16x8 ah[2], al[2];
#pragma unroll
            for (int mi = 0; mi < 2; ++mi) {
                const float* p = &sO1[mi * 16 + fr][kt * 32 + fq * 8];
                f32x4 v0 = *(const f32x4*)p;
                f32x4 v1 = *(const f32x4*)(p + 4);
                float vv[8] = {v0[0], v0[1], v0[2], v0[3], v1[0], v1[1], v1[2], v1[3]};
#pragma unroll
                for (int j = 0; j < 8; ++j) {
                    __bf16 h = (__bf16)vv[j];
                    ah[mi][j] = h; al[mi][j] = (__bf16)(vv[j] - (float)h);
                }
            }
            size_t rb = (size_t)(wid * 16 + fr) * 128 + kt * 32 + fq * 8;
            bf16x8 bh = *(const bf16x8*)(c2h + rb);
            bf16x8 bl = *(const bf16x8*)(c2l + rb);
#pragma unroll
            for (int mi = 0; mi < 2; ++mi) {
                acc[mi] = __builtin_amdgcn_mfma_f32_16x16x32_bf16(ah[mi], bh, acc[mi], 0, 0, 0);
                acc[mi] = __builtin_amdgcn_mfma_f32_16x16x32_bf16(ah[mi], bl, acc[mi], 0, 0, 0);
                acc[mi] = __builtin_amdgcn_mfma_f32_16x16x32_bf16(al[mi], bh, acc[mi], 0, 0, 0);
            }
        }
        int col = wid * 16 + fr;
        float bb = b2[col];
#pragma unroll
        for (int mi = 0; mi < 2; ++mi)
#pragma unroll
            for (int r = 0; r < 4; ++r)
                sO2[mi * 16 + fq * 4 + r][col] = fmaxf(acc[mi][r] + bb, 0.0f);
    }
    __syncthreads();

    // ---- stage 3: logits = O2 @ c3^T + b3
    if (wid < 2) {
        f32x4 acc = {};
#pragma unroll
        for (int kt = 0; kt < 2; ++kt) {
            const float* p = &sO2[wid * 16 + fr][kt * 32 + fq * 8];
            f32x4 v0 = *(const f32x4*)p;
            f32x4 v1 = *(const f32x4*)(p + 4);
            float vv[8] = {v0[0], v0[1], v0[2], v0[3], v1[0], v1[1], v1[2], v1[3]};
            bf16x8 ah, al;
#pragma unroll
            for (int j = 0; j < 8; ++j) {
                __bf16 h = (__bf16)vv[j];
                ah[j] = h; al[j] = (__bf16)(vv[j] - (float)h);
            }
            size_t rb = (size_t)fr * 64 + kt * 32 + fq * 8;
            bf16x8 bh = *(const bf16x8*)(c3h + rb);
            bf16x8 bl = *(const bf16x8*)(c3l + rb);
            acc = __builtin_amdgcn_mfma_f32_16x16x32_bf16(ah, bh, acc, 0, 0, 0);
            acc = __builtin_amdgcn_mfma_f32_16x16x32_bf16(ah, bl, acc, 0, 0, 0);
            acc = __builtin_amdgcn_mfma_f32_16x16x32_bf16(al, bh, acc, 0, 0, 0);
        }
        if (fr < 10) {
            float bb = b3[fr];
#pragma unroll
            for (int r = 0; r < 4; ++r) {
                int row = bm + wid * 16 + fq * 4 + r;
                if (row < NN) out[(size_t)row * 10 + fr] = acc[r] + bb;
            }
        }
    }
}

// ------------------------------------------------------------------
extern "C" void kernel_launch(void* const* d_in, const int* in_sizes, int n_in,
                              void* d_out, int out_size, void* d_ws, size_t ws_size,
                              hipStream_t stream)
{
    const float* x     = (const float*)d_in[0];
    const int*   eidx  = (const int*)d_in[1];
    const float* in_W  = (const float*)d_in[2];
    const float* in_b  = (const float*)d_in[3];
    const float* gcn_W = (const float*)d_in[4];
    const float* gcn_b = (const float*)d_in[5];
    const float* bn_g  = (const float*)d_in[6];
    const float* bn_be = (const float*)d_in[7];
    const float* bn_m  = (const float*)d_in[8];
    const float* bn_v  = (const float*)d_in[9];
    const float* c1_W  = (const float*)d_in[10];
    const float* c1_b  = (const float*)d_in[11];
    const float* c2_W  = (const float*)d_in[12];
    const float* c2_b  = (const float*)d_in[13];
    const float* c3_W  = (const float*)d_in[14];
    const float* c3_b  = (const float*)d_in[15];
    float* out = (float*)d_out;

    const int E = in_sizes[1] / 2;
    float* ws = (float*)d_ws;

    // ---- workspace layout ----
    float*  P   = ws;                 // 4 slices of NPH f32 (reused as h1,h2,hws)
    float*  h1  = P;
    float*  h2  = P + NPH;
    float*  hws = P + 2 * NPH;
    __bf16* hhi = (__bf16*)(P + 4 * NPH);
    __bf16* hlo = hhi + NPH;
    __bf16* wih = hlo + NPH;          // 256x2048
    __bf16* wil = wih + 524288;
    __bf16* gwh = wil + 524288;       // 768x256
    __bf16* gwl = gwh + 196608;
    __bf16* c1h = gwl + 196608;       // 128x256
    __bf16* c1l = c1h + 32768;
    __bf16* c2h = c1l + 32768;        // 64x128
    __bf16* c2l = c2h + 8192;
    __bf16* c3h = c2l + 8192;         // 16x64 (10 real rows)
    __bf16* c3l = c3h + 1024;
    float*    dinv = (float*)(c3l + 1024);
    unsigned* cnt  = (unsigned*)(dinv + NN);
    unsigned* off  = cnt + NN;
    unsigned* cur  = off + NN + 1;
    unsigned* flag = cur + NN;
    int*      csr  = (int*)(flag + 4);

    // ---- graph prep ----
    prep_zero_detect<<<40, 256, 0, stream>>>(eidx, cnt, flag);
    count_edges<<<(E + 255) / 256, 256, 0, stream>>>(eidx, flag, cnt, E);
    scan_dinv<<<1, 256, 0, stream>>>(cnt, off, cur, dinv, NN);
    fill_csr<<<(E + 255) / 256, 256, 0, stream>>>(eidx, flag, cur, csr, E);

    // ---- weight splits ----
    split_all<<<2980, 256, 0, stream>>>(in_W, gcn_W, c1_W, c2_W, c3_W,
                                        wih, wil, gwh, gwl, c1h, c1l, c2h, c2l, c3h, c3l);

    // ---- input projection ----
    inproj_gemm<<<dim3(NP / 64, 1, IPZ), 256, 0, stream>>>(x, wih, wil, P);
    inproj_epi<<<(int)(NPH / 1024), 256, 0, stream>>>(P, in_b, hhi, hlo);

    // ---- 3 GCN layers ----
    for (int i = 0; i < 3; ++i) {
        gemm_layer<<<dim3(NP / 64, 4), 256, 0, stream>>>(
            hhi, hlo, gwh + (size_t)i * 65536, gwl + (size_t)i * 65536, dinv, hws);
        const float* res = (i == 0) ? nullptr : (i == 1 ? h1 : h2);
        float* hf = (i == 0) ? h1 : (i == 1 ? h2 : nullptr);
        gcn_aggregate<<<2504, 256, 0, stream>>>(
            hws, res, dinv, off, csr,
            gcn_b + i * HID, bn_g + i * HID, bn_be + i * HID,
            bn_m + i * HID, bn_v + i * HID, hf, hhi, hlo);
    }
    zero_pad_rows<<<48, 256, 0, stream>>>(hhi, hlo);  // pad rows for classifier

    // ---- fused classifier ----
    classifier<<<NP / 32, 256, 0, stream>>>(hhi, hlo, c1h, c1l, c1_b,
                                            c2h, c2l, c2_b, c3h, c3l, c3_b, out);
}

// Round 9
// 327.750 us; speedup vs baseline: 1.1978x; 1.0500x over previous
//
#include <hip/hip_runtime.h>
#include <hip/hip_bf16.h>

#define NN   10000
#define NP   10048          // 157*64 padded rows
#define HID  256
#define BN_EPS 1e-5f
#define NPH  ((size_t)NP * 256)

typedef __bf16 bf16x4 __attribute__((ext_vector_type(4)));
typedef __bf16 bf16x8 __attribute__((ext_vector_type(8)));
typedef float  f32x4  __attribute__((ext_vector_type(4)));

__device__ __forceinline__ void gl_lds16(const void* gptr, void* lptr) {
    __builtin_amdgcn_global_load_lds(
        (const __attribute__((address_space(1))) void*)gptr,
        (__attribute__((address_space(3))) void*)lptr,
        16, 0, 0);
}

// ------------------------------------------------------------------
// Merged: cnt-zero + i64-layout detect (blocks 0..39) and weight hi/lo
// splits (blocks 40..3019).
__global__ void prep_split(const int* __restrict__ e, unsigned* __restrict__ cnt,
                           unsigned* __restrict__ flag,
                           const float* __restrict__ in_W, const float* __restrict__ gcn_W,
                           const float* __restrict__ c1_W, const float* __restrict__ c2_W,
                           const float* __restrict__ c3_W,
                           __bf16* __restrict__ wih, __bf16* __restrict__ wil,
                           __bf16* __restrict__ gwh, __bf16* __restrict__ gwl,
                           __bf16* __restrict__ c1h, __bf16* __restrict__ c1l,
                           __bf16* __restrict__ c2h, __bf16* __restrict__ c2l,
                           __bf16* __restrict__ c3h, __bf16* __restrict__ c3l) {
    if (blockIdx.x < 40) {
        int i = blockIdx.x * 256 + threadIdx.x;
        if (i < NN) cnt[i] = 0u;
        if (blockIdx.x == 0) {
            __shared__ int nz;
            if (threadIdx.x == 0) nz = 0;
            __syncthreads();
            if (e[2 * threadIdx.x + 1] != 0) nz = 1;
            __syncthreads();
            if (threadIdx.x == 0) *flag = (nz == 0) ? 1u : 0u;  // 1 => int64 layout
        }
        return;
    }
    int idx = (blockIdx.x - 40) * 256 + threadIdx.x;
    float v; __bf16 *dh, *dl; int o;
    if (idx < 524288)      { v = in_W[idx];          dh = wih; dl = wil; o = idx; }
    else if (idx < 720896) { o = idx - 524288; v = gcn_W[o]; dh = gwh; dl = gwl; }
    else if (idx < 753664) { o = idx - 720896; v = c1_W[o];  dh = c1h; dl = c1l; }
    else if (idx < 761856) { o = idx - 753664; v = c2_W[o];  dh = c2h; dl = c2l; }
    else                   { o = idx - 761856; int r = o >> 6, c = o & 63;
                             v = (r < 10) ? c3_W[r * 64 + c] : 0.0f; dh = c3h; dl = c3l; }
    __bf16 h = (__bf16)v;
    dh[o] = h;
    dl[o] = (__bf16)(v - (float)h);
}

__device__ __forceinline__ int edge_val(const int* e, unsigned f, long idx) {
    return f ? e[2 * idx] : e[idx];
}

__global__ void count_edges(const int* __restrict__ e, const unsigned* __restrict__ flag,
                            unsigned* __restrict__ cnt, int E) {
    int i = blockIdx.x * blockDim.x + threadIdx.x;
    if (i >= E) return;
    unsigned f = *flag;
    atomicAdd(&cnt[edge_val(e, f, (long)E + i)], 1u);
}

__global__ void scan_dinv(const unsigned* __restrict__ cnt, unsigned* __restrict__ off,
                          unsigned* __restrict__ cur, float* __restrict__ dinv, int n) {
    __shared__ unsigned partial[256];
    int t = threadIdx.x;
    int chunk = (n + 255) / 256;
    int lo = t * chunk;
    int hi = lo + chunk; if (hi > n) hi = n; if (lo > n) lo = n;
    unsigned s = 0;
    for (int i = lo; i < hi; ++i) s += cnt[i];
    partial[t] = s;
    __syncthreads();
    for (int d = 1; d < 256; d <<= 1) {
        unsigned v = (t >= d) ? partial[t - d] : 0u;
        __syncthreads();
        partial[t] += v;
        __syncthreads();
    }
    unsigned base = (t == 0) ? 0u : partial[t - 1];
    for (int i = lo; i < hi; ++i) {
        off[i] = base; cur[i] = base;
        dinv[i] = rsqrtf((float)cnt[i] + 1.0f);
        base += cnt[i];
    }
    if (t == 255) off[n] = base;
}

__global__ void fill_csr(const int* __restrict__ e, const unsigned* __restrict__ flag,
                         unsigned* __restrict__ cur, int* __restrict__ csr_src, int E) {
    int i = blockIdx.x * blockDim.x + threadIdx.x;
    if (i >= E) return;
    unsigned f = *flag;
    int src = edge_val(e, f, (long)i);
    int dst = edge_val(e, f, (long)E + i);
    unsigned pos = atomicAdd(&cur[dst], 1u);
    csr_src[pos] = src;
}

// ------------------------------------------------------------------
// Input projection (measured-best variant, ~80 us): BM=64 x BN=256,
// split-K=4, 2-phase pipelined, double-buffered LDS; B hi+lo via
// global_load_lds; A fp32 loads issued early / converted late.
#define IPZ 4
#define IPKC 512
__global__ __launch_bounds__(256) void inproj_gemm(
    const float* __restrict__ A,
    const __bf16* __restrict__ Bh, const __bf16* __restrict__ Bl,
    float* __restrict__ P)
{
    __shared__ __align__(16) __bf16 sAh[2][2048], sAl[2][2048];
    __shared__ __align__(16) __bf16 sBh[2][8192], sBl[2][8192];

    const int tid = threadIdx.x, wid = tid >> 6, lane = tid & 63;
    const int fr = lane & 15, fq = lane >> 4;
    const int bm = blockIdx.x * 64;
    const int kbase = blockIdx.z * IPKC;
    const int wn = wid * 64;

    f32x4 acc[4][4] = {};

    const int rs = tid >> 2, cq = tid & 3;
    const int gr = min(bm + rs, NN - 1);
    const float* aptr = A + (size_t)gr * 2048 + cq * 8;
    const int scA = rs * 32 + ((cq ^ ((rs >> 1) & 3)) << 3);
    const int brow_l = lane >> 2, bch = lane & 3;

    float av[8];
    int cur = 0;

    {   // prologue: stage tile 0
        float4 v0 = *(const float4*)(aptr + kbase);
        float4 v1 = *(const float4*)(aptr + kbase + 4);
        av[0]=v0.x; av[1]=v0.y; av[2]=v0.z; av[3]=v0.w;
        av[4]=v1.x; av[5]=v1.y; av[6]=v1.z; av[7]=v1.w;
#pragma unroll
        for (int j = 0; j < 4; ++j) {
            int slice = wid * 4 + j;
            int row = slice * 16 + brow_l;
            int lc = bch ^ ((row >> 1) & 3);
            size_t goff = (size_t)row * 2048 + kbase + lc * 8;
            gl_lds16(Bh + goff, &sBh[0][slice * 512]);
            gl_lds16(Bl + goff, &sBl[0][slice * 512]);
        }
        bf16x8 hv, lv;
#pragma unroll
        for (int j = 0; j < 8; ++j) {
            __bf16 h = (__bf16)av[j];
            hv[j] = h; lv[j] = (__bf16)(av[j] - (float)h);
        }
        *(bf16x8*)&sAh[0][scA] = hv;
        *(bf16x8*)&sAl[0][scA] = lv;
    }
    __syncthreads();

    for (int kt = 0; kt < IPKC / 32; ++kt) {
        const bool more = (kt + 1) < IPKC / 32;
        const int nk = kbase + (kt + 1) * 32;
        if (more) {
            float4 v0 = *(const float4*)(aptr + nk);
            float4 v1 = *(const float4*)(aptr + nk + 4);
            av[0]=v0.x; av[1]=v0.y; av[2]=v0.z; av[3]=v0.w;
            av[4]=v1.x; av[5]=v1.y; av[6]=v1.z; av[7]=v1.w;
#pragma unroll
            for (int j = 0; j < 4; ++j) {
                int slice = wid * 4 + j;
                int row = slice * 16 + brow_l;
                int lc = bch ^ ((row >> 1) & 3);
                size_t goff = (size_t)row * 2048 + nk + lc * 8;
                gl_lds16(Bh + goff, &sBh[cur ^ 1][slice * 512]);
                gl_lds16(Bl + goff, &sBl[cur ^ 1][slice * 512]);
            }
        }
        bf16x8 bh[4], bl[4];
#pragma unroll
        for (int ni = 0; ni < 4; ++ni) {
            int r = wn + ni * 16 + fr;
            int e = r * 32 + ((fq ^ ((r >> 1) & 3)) << 3);
            bh[ni] = *(const bf16x8*)&sBh[cur][e];
            bl[ni] = *(const bf16x8*)&sBl[cur][e];
        }
#pragma unroll
        for (int mi = 0; mi < 4; ++mi) {
            int r = mi * 16 + fr;
            int e = r * 32 + ((fq ^ ((r >> 1) & 3)) << 3);
            bf16x8 ah = *(const bf16x8*)&sAh[cur][e];
            bf16x8 al = *(const bf16x8*)&sAl[cur][e];
#pragma unroll
            for (int ni = 0; ni < 4; ++ni) {
                acc[mi][ni] = __builtin_amdgcn_mfma_f32_16x16x32_bf16(ah, bh[ni], acc[mi][ni], 0, 0, 0);
                acc[mi][ni] = __builtin_amdgcn_mfma_f32_16x16x32_bf16(ah, bl[ni], acc[mi][ni], 0, 0, 0);
                acc[mi][ni] = __builtin_amdgcn_mfma_f32_16x16x32_bf16(al, bh[ni], acc[mi][ni], 0, 0, 0);
            }
        }
        if (more) {
            bf16x8 hv, lv;
#pragma unroll
            for (int j = 0; j < 8; ++j) {
                __bf16 h = (__bf16)av[j];
                hv[j] = h; lv[j] = (__bf16)(av[j] - (float)h);
            }
            *(bf16x8*)&sAh[cur ^ 1][scA] = hv;
            *(bf16x8*)&sAl[cur ^ 1][scA] = lv;
        }
        __syncthreads();
        cur ^= 1;
    }

    float* Pz = P + (size_t)blockIdx.z * NPH;
#pragma unroll
    for (int mi = 0; mi < 4; ++mi) {
        int row0 = bm + mi * 16 + fq * 4;
#pragma unroll
        for (int ni = 0; ni < 4; ++ni) {
            int col = wn + ni * 16 + fr;
#pragma unroll
            for (int r = 0; r < 4; ++r)
                Pz[(size_t)(row0 + r) * 256 + col] = acc[mi][ni][r];
        }
    }
}

// reduce 4 partials + bias + relu -> bf16 hi/lo planes (zero pad rows)
__global__ void inproj_epi(const float* __restrict__ P, const float* __restrict__ b,
                           __bf16* __restrict__ hhi, __bf16* __restrict__ hlo) {
    int t = blockIdx.x * 256 + threadIdx.x;
    size_t idx = (size_t)t * 4;
    int row = (int)(idx >> 8), col = (int)(idx & 255);
    float v[4] = {0, 0, 0, 0};
    if (row < NN) {
        const float* p = P + idx;
        float4 a0 = *(const float4*)(p);
        float4 a1 = *(const float4*)(p + NPH);
        float4 a2 = *(const float4*)(p + 2 * NPH);
        float4 a3 = *(const float4*)(p + 3 * NPH);
        v[0] = fmaxf(a0.x + a1.x + a2.x + a3.x + b[col + 0], 0.0f);
        v[1] = fmaxf(a0.y + a1.y + a2.y + a3.y + b[col + 1], 0.0f);
        v[2] = fmaxf(a0.z + a1.z + a2.z + a3.z + b[col + 2], 0.0f);
        v[3] = fmaxf(a0.w + a1.w + a2.w + a3.w + b[col + 3], 0.0f);
    }
    bf16x4 hv, lv;
#pragma unroll
    for (int j = 0; j < 4; ++j) {
        __bf16 h = (__bf16)v[j];
        hv[j] = h; lv[j] = (__bf16)(v[j] - (float)h);
    }
    *(bf16x4*)&hhi[idx] = hv;
    *(bf16x4*)&hlo[idx] = lv;
}

// ------------------------------------------------------------------
// Layer GEMM (K=256): no LDS, per-lane direct fragment loads.
// Epilogue pre-scales each output row by dinv[row]  ->  hws = (h @ W^T) * dinv
__global__ __launch_bounds__(256) void gemm_layer(
    const __bf16* __restrict__ Ah, const __bf16* __restrict__ Al,
    const __bf16* __restrict__ Bh, const __bf16* __restrict__ Bl,
    const float* __restrict__ dinv, float* __restrict__ Cf)
{
    const int tid = threadIdx.x, wid = tid >> 6, lane = tid & 63;
    const int fr = lane & 15, fq = lane >> 4;
    const int wr = wid >> 1, wc = wid & 1;
    const int bm = blockIdx.x * 64, bn = blockIdx.y * 64;

    f32x4 acc[2][2] = {};
    size_t ra[2], rb[2];
#pragma unroll
    for (int mi = 0; mi < 2; ++mi) ra[mi] = (size_t)(bm + wr * 32 + mi * 16 + fr) * 256 + fq * 8;
#pragma unroll
    for (int ni = 0; ni < 2; ++ni) rb[ni] = (size_t)(bn + wc * 32 + ni * 16 + fr) * 256 + fq * 8;

#pragma unroll
    for (int kt = 0; kt < 8; ++kt) {
        bf16x8 ah[2], al[2], bh[2], bl[2];
#pragma unroll
        for (int mi = 0; mi < 2; ++mi) {
            ah[mi] = *(const bf16x8*)(Ah + ra[mi] + kt * 32);
            al[mi] = *(const bf16x8*)(Al + ra[mi] + kt * 32);
        }
#pragma unroll
        for (int ni = 0; ni < 2; ++ni) {
            bh[ni] = *(const bf16x8*)(Bh + rb[ni] + kt * 32);
            bl[ni] = *(const bf16x8*)(Bl + rb[ni] + kt * 32);
        }
#pragma unroll
        for (int mi = 0; mi < 2; ++mi)
#pragma unroll
            for (int ni = 0; ni < 2; ++ni) {
                acc[mi][ni] = __builtin_amdgcn_mfma_f32_16x16x32_bf16(ah[mi], bh[ni], acc[mi][ni], 0, 0, 0);
                acc[mi][ni] = __builtin_amdgcn_mfma_f32_16x16x32_bf16(ah[mi], bl[ni], acc[mi][ni], 0, 0, 0);
                acc[mi][ni] = __builtin_amdgcn_mfma_f32_16x16x32_bf16(al[mi], bh[ni], acc[mi][ni], 0, 0, 0);
            }
    }

    float dv[2][4];
#pragma unroll
    for (int mi = 0; mi < 2; ++mi)
#pragma unroll
        for (int r = 0; r < 4; ++r) {
            int row = bm + wr * 32 + mi * 16 + fq * 4 + r;
            dv[mi][r] = (row < NN) ? dinv[row] : 0.0f;
        }

#pragma unroll
    for (int mi = 0; mi < 2; ++mi)
#pragma unroll
        for (int ni = 0; ni < 2; ++ni) {
            int col = bn + wc * 32 + ni * 16 + fr;
#pragma unroll
            for (int r = 0; r < 4; ++r) {
                int row = bm + wr * 32 + mi * 16 + fq * 4 + r;
                if (row < NN) Cf[(size_t)row * 256 + col] = acc[mi][ni][r] * dv[mi][r];
            }
        }
}

// ------------------------------------------------------------------
// XCD-pinned, feature-chunked GCN aggregate (v3: no shfl).
// 4 chunks of 64 features; per-chunk gather set = 10000*256B = 2.56 MB < 4 MB
// per-XCD L2; chunk = xcd>>1. 16 lanes/node, f32x4/lane.
// Edge ids read DIRECTLY by all 16 lanes (same addr -> HW broadcast, L2-hot
// sequential lines); 4 independent accumulators break the dependent-add chain.
__global__ __launch_bounds__(256) void gcn_aggregate(
    const float* __restrict__ hws, const float* __restrict__ res,
    const float* __restrict__ dinv, const unsigned* __restrict__ off,
    const int* __restrict__ csr,
    const float* __restrict__ bias, const float* __restrict__ gamma,
    const float* __restrict__ beta, const float* __restrict__ mean,
    const float* __restrict__ var,
    float* __restrict__ hf, __bf16* __restrict__ hhi, __bf16* __restrict__ hlo)
{
    const int xcd = blockIdx.x & 7;
    const int chunk = xcd >> 1;                       // 0..3
    const int nb = (blockIdx.x >> 3) * 2 + (xcd & 1); // node-block 0..625
    if (nb >= 625) return;                            // 625*16 = 10000 exactly

    const int tid = threadIdx.x;
    const int g = tid >> 4;                           // node-in-block 0..15
    const int q = tid & 15;                           // feature lane 0..15
    const int node = nb * 16 + g;
    const int f = chunk * 64 + q * 4;
    const size_t rowb = (size_t)node * HID + f;

    const float dn = dinv[node];
    const unsigned j0 = off[node], j1 = off[node + 1];

    f32x4 a0 = *(const f32x4*)(hws + rowb);           // self term (pre-scaled)
    f32x4 a1 = {0.f, 0.f, 0.f, 0.f};
    f32x4 a2 = {0.f, 0.f, 0.f, 0.f};
    f32x4 a3 = {0.f, 0.f, 0.f, 0.f};

    unsigned j = j0;
    for (; j + 4 <= j1; j += 4) {
        int s0 = csr[j + 0];
        int s1 = csr[j + 1];
        int s2 = csr[j + 2];
        int s3 = csr[j + 3];
        a0 += *(const f32x4*)(hws + (size_t)s0 * HID + f);
        a1 += *(const f32x4*)(hws + (size_t)s1 * HID + f);
        a2 += *(const f32x4*)(hws + (size_t)s2 * HID + f);
        a3 += *(const f32x4*)(hws + (size_t)s3 * HID + f);
    }
    for (; j < j1; ++j) {
        int s = csr[j];
        a1 += *(const f32x4*)(hws + (size_t)s * HID + f);
    }
    f32x4 acc = (a0 + a1) + (a2 + a3);

    f32x4 b4  = *(const f32x4*)(bias + f);
    f32x4 m4  = *(const f32x4*)(mean + f);
    f32x4 v4  = *(const f32x4*)(var + f);
    f32x4 g4  = *(const f32x4*)(gamma + f);
    f32x4 be4 = *(const f32x4*)(beta + f);
    f32x4 r4 = {0.0f, 0.0f, 0.0f, 0.0f};
    if (res) r4 = *(const f32x4*)(res + rowb);

    f32x4 o;
    bf16x4 hv, lv;
#pragma unroll
    for (int jj = 0; jj < 4; ++jj) {
        float t = dn * acc[jj] + b4[jj];
        t = (t - m4[jj]) * rsqrtf(v4[jj] + BN_EPS) * g4[jj] + be4[jj];
        t = fmaxf(t, 0.0f);
        t += r4[jj];
        o[jj] = t;
        __bf16 h = (__bf16)t;
        hv[jj] = h; lv[jj] = (__bf16)(t - (float)h);
    }
    if (hf) *(f32x4*)(hf + rowb) = o;
    *(bf16x4*)&hhi[rowb] = hv;
    *(bf16x4*)&hlo[rowb] = lv;
}

// ------------------------------------------------------------------
// Fused classifier: 32-row tile, h -> O1(LDS) -> O2(LDS) -> logits.
__global__ __launch_bounds__(256) void classifier(
    const __bf16* __restrict__ Ah, const __bf16* __restrict__ Al,
    const __bf16* __restrict__ c1h, const __bf16* __restrict__ c1l, const float* __restrict__ b1,
    const __bf16* __restrict__ c2h, const __bf16* __restrict__ c2l, const float* __restrict__ b2,
    const __bf16* __restrict__ c3h, const __bf16* __restrict__ c3l, const float* __restrict__ b3,
    float* __restrict__ out)
{
    __shared__ __align__(16) float sO1[32][132];
    __shared__ __align__(16) float sO2[32][68];

    const int tid = threadIdx.x, wid = tid >> 6, lane = tid & 63;
    const int fr = lane & 15, fq = lane >> 4;
    const int bm = blockIdx.x * 32;

    // ---- stage 1: O1 = relu(h @ c1^T + b1)   M=32 N=128 K=256
    {
        f32x4 acc[2][2] = {};
        size_t ra[2], rb[2];
#pragma unroll
        for (int mi = 0; mi < 2; ++mi) ra[mi] = (size_t)(bm + mi * 16 + fr) * 256 + fq * 8;
#pragma unroll
        for (int ni = 0; ni < 2; ++ni) rb[ni] = (size_t)(wid * 32 + ni * 16 + fr) * 256 + fq * 8;
#pragma unroll
        for (int kt = 0; kt < 8; ++kt) {
            bf16x8 ah[2], al[2], bh[2], bl[2];
#pragma unroll
            for (int mi = 0; mi < 2; ++mi) {
                ah[mi] = *(const bf16x8*)(Ah + ra[mi] + kt * 32);
                al[mi] = *(const bf16x8*)(Al + ra[mi] + kt * 32);
            }
#pragma unroll
            for (int ni = 0; ni < 2; ++ni) {
                bh[ni] = *(const bf16x8*)(c1h + rb[ni] + kt * 32);
                bl[ni] = *(const bf16x8*)(c1l + rb[ni] + kt * 32);
            }
#pragma unroll
            for (int mi = 0; mi < 2; ++mi)
#pragma unroll
                for (int ni = 0; ni < 2; ++ni) {
                    acc[mi][ni] = __builtin_amdgcn_mfma_f32_16x16x32_bf16(ah[mi], bh[ni], acc[mi][ni], 0, 0, 0);
                    acc[mi][ni] = __builtin_amdgcn_mfma_f32_16x16x32_bf16(ah[mi], bl[ni], acc[mi][ni], 0, 0, 0);
                    acc[mi][ni] = __builtin_amdgcn_mfma_f32_16x16x32_bf16(al[mi], bh[ni], acc[mi][ni], 0, 0, 0);
                }
        }
#pragma unroll
        for (int mi = 0; mi < 2; ++mi)
#pragma unroll
            for (int ni = 0; ni < 2; ++ni) {
                int col = wid * 32 + ni * 16 + fr;
                float bb = b1[col];
#pragma unroll
                for (int r = 0; r < 4; ++r)
                    sO1[mi * 16 + fq * 4 + r][col] = fmaxf(acc[mi][ni][r] + bb, 0.0f);
            }
    }
    __syncthreads();

    // ---- stage 2: O2 = relu(O1 @ c2^T + b2)   M=32 N=64 K=128
    {
        f32x4 acc[2] = {};
#pragma unroll
        for (int kt = 0; kt < 4; ++kt) {
            bf16x8 ah[2], al[2];
#pragma unroll
            for (int mi = 0; mi < 2; ++mi) {
                const float* p = &sO1[mi * 16 + fr][kt * 32 + fq * 8];
                f32x4 v0 = *(const f32x4*)p;
                f32x4 v1 = *(const f32x4*)(p + 4);
                float vv[8] = {v0[0], v0[1], v0[2], v0[3], v1[0], v1[1], v1[2], v1[3]};
#pragma unroll
                for (int j = 0; j < 8; ++j) {
                    __bf16 h = (__bf16)vv[j];
                    ah[mi][j] = h; al[mi][j] = (__bf16)(vv[j] - (float)h);
                }
            }
            size_t rb = (size_t)(wid * 16 + fr) * 128 + kt * 32 + fq * 8;
            bf16x8 bh = *(const bf16x8*)(c2h + rb);
            bf16x8 bl = *(const bf16x8*)(c2l + rb);
#pragma unroll
            for (int mi = 0; mi < 2; ++mi) {
                acc[mi] = __builtin_amdgcn_mfma_f32_16x16x32_bf16(ah[mi], bh, acc[mi], 0, 0, 0);
                acc[mi] = __builtin_amdgcn_mfma_f32_16x16x32_bf16(ah[mi], bl, acc[mi], 0, 0, 0);
                acc[mi] = __builtin_amdgcn_mfma_f32_16x16x32_bf16(al[mi], bh, acc[mi], 0, 0, 0);
            }
        }
        int col = wid * 16 + fr;
        float bb = b2[col];
#pragma unroll
        for (int mi = 0; mi < 2; ++mi)
#pragma unroll
            for (int r = 0; r < 4; ++r)
                sO2[mi * 16 + fq * 4 + r][col] = fmaxf(acc[mi][r] + bb, 0.0f);
    }
    __syncthreads();

    // ---- stage 3: logits = O2 @ c3^T + b3
    if (wid < 2) {
        f32x4 acc = {};
#pragma unroll
        for (int kt = 0; kt < 2; ++kt) {
            const float* p = &sO2[wid * 16 + fr][kt * 32 + fq * 8];
            f32x4 v0 = *(const f32x4*)p;
            f32x4 v1 = *(const f32x4*)(p + 4);
            float vv[8] = {v0[0], v0[1], v0[2], v0[3], v1[0], v1[1], v1[2], v1[3]};
            bf16x8 ah, al;
#pragma unroll
            for (int j = 0; j < 8; ++j) {
                __bf16 h = (__bf16)vv[j];
                ah[j] = h; al[j] = (__bf16)(vv[j] - (float)h);
            }
            size_t rb = (size_t)fr * 64 + kt * 32 + fq * 8;
            bf16x8 bh = *(const bf16x8*)(c3h + rb);
            bf16x8 bl = *(const bf16x8*)(c3l + rb);
            acc = __builtin_amdgcn_mfma_f32_16x16x32_bf16(ah, bh, acc, 0, 0, 0);
            acc = __builtin_amdgcn_mfma_f32_16x16x32_bf16(ah, bl, acc, 0, 0, 0);
            acc = __builtin_amdgcn_mfma_f32_16x16x32_bf16(al, bh, acc, 0, 0, 0);
        }
        if (fr < 10) {
            float bb = b3[fr];
#pragma unroll
            for (int r = 0; r < 4; ++r) {
                int row = bm + wid * 16 + fq * 4 + r;
                if (row < NN) out[(size_t)row * 10 + fr] = acc[r] + bb;
            }
        }
    }
}

// ------------------------------------------------------------------
extern "C" void kernel_launch(void* const* d_in, const int* in_sizes, int n_in,
                              void* d_out, int out_size, void* d_ws, size_t ws_size,
                              hipStream_t stream)
{
    const float* x     = (const float*)d_in[0];
    const int*   eidx  = (const int*)d_in[1];
    const float* in_W  = (const float*)d_in[2];
    const float* in_b  = (const float*)d_in[3];
    const float* gcn_W = (const float*)d_in[4];
    const float* gcn_b = (const float*)d_in[5];
    const float* bn_g  = (const float*)d_in[6];
    const float* bn_be = (const float*)d_in[7];
    const float* bn_m  = (const float*)d_in[8];
    const float* bn_v  = (const float*)d_in[9];
    const float* c1_W  = (const float*)d_in[10];
    const float* c1_b  = (const float*)d_in[11];
    const float* c2_W  = (const float*)d_in[12];
    const float* c2_b  = (const float*)d_in[13];
    const float* c3_W  = (const float*)d_in[14];
    const float* c3_b  = (const float*)d_in[15];
    float* out = (float*)d_out;

    const int E = in_sizes[1] / 2;
    float* ws = (float*)d_ws;

    // ---- workspace layout ----
    float*  P   = ws;                 // 4 slices of NPH f32 (reused as h1,h2,hws)
    float*  h1  = P;
    float*  h2  = P + NPH;
    float*  hws = P + 2 * NPH;
    __bf16* hhi = (__bf16*)(P + 4 * NPH);
    __bf16* hlo = hhi + NPH;
    __bf16* wih = hlo + NPH;          // 256x2048
    __bf16* wil = wih + 524288;
    __bf16* gwh = wil + 524288;       // 768x256
    __bf16* gwl = gwh + 196608;
    __bf16* c1h = gwl + 196608;       // 128x256
    __bf16* c1l = c1h + 32768;
    __bf16* c2h = c1l + 32768;        // 64x128
    __bf16* c2l = c2h + 8192;
    __bf16* c3h = c2l + 8192;         // 16x64 (10 real rows)
    __bf16* c3l = c3h + 1024;
    float*    dinv = (float*)(c3l + 1024);
    unsigned* cnt  = (unsigned*)(dinv + NN);
    unsigned* off  = cnt + NN;
    unsigned* cur  = off + NN + 1;
    unsigned* flag = cur + NN;
    int*      csr  = (int*)(flag + 4);

    // ---- graph prep + weight splits (merged first launch) ----
    prep_split<<<3020, 256, 0, stream>>>(eidx, cnt, flag, in_W, gcn_W, c1_W, c2_W, c3_W,
                                         wih, wil, gwh, gwl, c1h, c1l, c2h, c2l, c3h, c3l);
    count_edges<<<(E + 255) / 256, 256, 0, stream>>>(eidx, flag, cnt, E);
    scan_dinv<<<1, 256, 0, stream>>>(cnt, off, cur, dinv, NN);
    fill_csr<<<(E + 255) / 256, 256, 0, stream>>>(eidx, flag, cur, csr, E);

    // ---- input projection ----
    inproj_gemm<<<dim3(NP / 64, 1, IPZ), 256, 0, stream>>>(x, wih, wil, P);
    inproj_epi<<<(int)(NPH / 1024), 256, 0, stream>>>(P, in_b, hhi, hlo);

    // ---- 3 GCN layers ----
    for (int i = 0; i < 3; ++i) {
        gemm_layer<<<dim3(NP / 64, 4), 256, 0, stream>>>(
            hhi, hlo, gwh + (size_t)i * 65536, gwl + (size_t)i * 65536, dinv, hws);
        const float* res = (i == 0) ? nullptr : (i == 1 ? h1 : h2);
        float* hf = (i == 0) ? h1 : (i == 1 ? h2 : nullptr);
        gcn_aggregate<<<2504, 256, 0, stream>>>(
            hws, res, dinv, off, csr,
            gcn_b + i * HID, bn_g + i * HID, bn_be + i * HID,
            bn_m + i * HID, bn_v + i * HID, hf, hhi, hlo);
    }

    // ---- fused classifier ----
    classifier<<<NP / 32, 256, 0, stream>>>(hhi, hlo, c1h, c1l, c1_b,
                                            c2h, c2l, c2_b, c3h, c3l, c3_b, out);
}